// Round 1
// baseline (3020.081 us; speedup 1.0000x reference)
//
#include <hip/hip_runtime.h>
#include <hip/hip_bf16.h>

#define NB   16      // batch
#define FDIM 2048    // lstm hidden
#define GDIM 8192    // 4*FDIM gates
#define KK2  4096    // concat K
#define WSEQ 32      // seq len
#define CDIM 256
#define CBD  64
#define HGT  32

typedef __bf16 bf16x8 __attribute__((ext_vector_type(8)));
typedef float  f32x4  __attribute__((ext_vector_type(4)));
typedef __hip_bfloat16 bf16_t;

__device__ __forceinline__ float sigf(float x) { return 1.f / (1.f + __expf(-x)); }

// ---------------------------------------------------------------------------
// Pack [w_ih | w_hh] (each 8192x2048 fp32 row-major, row=r out-feature, col=k)
// into bf16 MFMA-B fragment order:
//   P[tile(r0/16)][kc(k0/32)][lane][8]  where lane l supplies
//   B[k = kc*32 + (l>>4)*8 + i][col = r0 + (l&15)]
// ---------------------------------------------------------------------------
__global__ void pack_w(const float* __restrict__ wih0, const float* __restrict__ whh0,
                       const float* __restrict__ wih1, const float* __restrict__ whh1,
                       bf16_t* __restrict__ L0, bf16_t* __restrict__ L1) {
    size_t idx = (size_t)blockIdx.x * blockDim.x + threadIdx.x; // 2*512*128*64 total
    int lane = idx & 63;
    int kc   = (idx >> 6) & 127;
    int tile = (idx >> 13) & 511;
    int mat  = (int)(idx >> 22);
    if (mat > 1) return;
    int r    = tile * 16 + (lane & 15);
    int kcol = kc * 32 + (lane >> 4) * 8;
    const float* wih = mat ? wih1 : wih0;
    const float* whh = mat ? whh1 : whh0;
    const float* src; int col;
    if (kcol < FDIM) { src = wih; col = kcol; } else { src = whh; col = kcol - FDIM; }
    const float* s = src + (size_t)r * FDIM + col;
    bf16_t* dst = (mat ? L1 : L0) + ((size_t)(tile * 128 + kc) * 64 + lane) * 8;
#pragma unroll
    for (int i = 0; i < 8; ++i) dst[i] = __float2bfloat16(s[i]);
}

__global__ void bias_k(const float* __restrict__ bih0, const float* __restrict__ bhh0,
                       const float* __restrict__ bih1, const float* __restrict__ bhh1,
                       float* __restrict__ b0, float* __restrict__ b1) {
    int i = blockIdx.x * blockDim.x + threadIdx.x;
    if (i < GDIM)            b0[i] = bih0[i] + bhh0[i];
    else if (i < 2 * GDIM) { int j = i - GDIM; b1[j] = bih1[j] + bhh1[j]; }
}

// ---------------------------------------------------------------------------
// 1x1 conv-in + pack sequence: seqb[t][n][f] (bf16), f = h*64 + cb
// one block per (n,t); latent[n][:, t, :] staged in LDS
// ---------------------------------------------------------------------------
__global__ __launch_bounds__(256) void conv_in(const float* __restrict__ latent,
                        const float* __restrict__ w_in, const float* __restrict__ b_in,
                        bf16_t* __restrict__ seqb) {
    __shared__ float lat[CDIM * HGT]; // [c][h] 32 KiB
    int b = blockIdx.x; int n = b >> 5; int t = b & 31;
    int tid = threadIdx.x;
    for (int i = 0; i < 32; ++i) {
        int flat = i * 256 + tid;         // c*32+h
        int c = flat >> 5, h = flat & 31;
        lat[flat] = latent[(((size_t)n * CDIM + c) * WSEQ + t) * HGT + h];
    }
    __syncthreads();
    int cb = tid & 63;
    int hb = tid >> 6;
    float acc[8];
#pragma unroll
    for (int k = 0; k < 8; ++k) acc[k] = b_in[cb];
    for (int c = 0; c < CDIM; ++c) {
        float wv = w_in[cb * CDIM + c];
#pragma unroll
        for (int k = 0; k < 8; ++k) acc[k] += lat[c * HGT + (hb + k * 4)] * wv;
    }
#pragma unroll
    for (int k = 0; k < 8; ++k) {
        int f = k * 256 + tid;  // h = f>>6 == hb+k*4, cb = f&63
        seqb[((size_t)t * NB + n) * FDIM + f] = __float2bfloat16(acc[k]);
    }
}

// ---------------------------------------------------------------------------
// X0pre[t][n][r] = seq[t] @ w_ih0^T   (no bias; bias added in cell)
// block: mtg=b>>7 covers 8 t-tiles, ng=b&127, wave -> ntile = ng*4+wave
// ---------------------------------------------------------------------------
__global__ __launch_bounds__(256) void x0_gemm(const bf16_t* __restrict__ seqb,
                                               const bf16_t* __restrict__ L0,
                                               float* __restrict__ x0) {
    int b = blockIdx.x;
    int mtg = b >> 7;
    int ng  = b & 127;
    int wave = threadIdx.x >> 6;
    int l = threadIdx.x & 63;
    int ntile = ng * 4 + wave;
    int la = l & 15, kg = l >> 4;
    f32x4 acc[8];
#pragma unroll
    for (int i = 0; i < 8; ++i) acc[i] = (f32x4){0.f, 0.f, 0.f, 0.f};
    for (int kc = 0; kc < 64; ++kc) {   // K = 2048 (w_ih0 half of L0cat)
        bf16x8 bf = *(const bf16x8*)(L0 + ((size_t)(ntile * 128 + kc) * 64 + l) * 8);
#pragma unroll
        for (int i = 0; i < 8; ++i) {
            int mt = mtg * 8 + i;
            bf16x8 af = *(const bf16x8*)(seqb + ((size_t)mt * 16 + la) * FDIM + kc * 32 + kg * 8);
            acc[i] = __builtin_amdgcn_mfma_f32_16x16x32_bf16(af, bf, acc[i], 0, 0, 0);
        }
    }
#pragma unroll
    for (int i = 0; i < 8; ++i) {
        int mt = mtg * 8 + i;
#pragma unroll
        for (int q = 0; q < 4; ++q) {
            int m = kg * 4 + q;
            x0[((size_t)mt * 16 + m) * GDIM + ntile * 16 + la] = acc[i][q];
        }
    }
}

// ---------------------------------------------------------------------------
// One LSTM phase (one layer at one step):
//   g[m][r] = A[m][:] @ Bcat[r][:] (+ xpre) + bias ; cell update ; write h,c
// grid 128 blocks (j-tile of 16 features), 8 waves = 4 gates x 2 K-halves
// A row stride = 4096 (both a-buffers are [16][4096]); kcStart in 32-chunks.
// ---------------------------------------------------------------------------
__global__ __launch_bounds__(512) void phase_k(
        const bf16_t* __restrict__ A, const bf16_t* __restrict__ Bp,
        const float* __restrict__ xpre, const float* __restrict__ bias,
        float* __restrict__ cbuf,
        bf16_t* __restrict__ hA, bf16_t* __restrict__ hB,
        float* __restrict__ seqSlot,
        int kcStart, int kcCount) {
    __shared__ float part[8][16][16];
    int jt = blockIdx.x;                 // 0..127
    int tid = threadIdx.x;
    int wave = tid >> 6, l = tid & 63;
    int g = wave >> 1, kh = wave & 1;
    int ntile = g * 128 + jt;
    int la = l & 15, kg = l >> 4;
    int half = kcCount >> 1;
    int kc0 = kcStart + kh * half;
    f32x4 acc = (f32x4){0.f, 0.f, 0.f, 0.f};
    const bf16_t* Arow = A + (size_t)la * KK2;
    for (int kc = kc0; kc < kc0 + half; ++kc) {
        bf16x8 af = *(const bf16x8*)(Arow + kc * 32 + kg * 8);
        bf16x8 bf = *(const bf16x8*)(Bp + ((size_t)(ntile * 128 + kc) * 64 + l) * 8);
        acc = __builtin_amdgcn_mfma_f32_16x16x32_bf16(af, bf, acc, 0, 0, 0);
    }
#pragma unroll
    for (int q = 0; q < 4; ++q) part[wave][kg * 4 + q][la] = acc[q];
    __syncthreads();
    if (tid < 256) {
        int m = tid >> 4, jl = tid & 15;
        int j = jt * 16 + jl;
        float gv[4];
#pragma unroll
        for (int gg = 0; gg < 4; ++gg) {
            float v = part[gg * 2][m][jl] + part[gg * 2 + 1][m][jl] + bias[gg * FDIM + j];
            if (xpre) v += xpre[(size_t)m * GDIM + gg * FDIM + j];
            gv[gg] = v;
        }
        float c  = cbuf[m * FDIM + j];
        float cn = sigf(gv[1]) * c + sigf(gv[0]) * tanhf(gv[2]);
        float h  = sigf(gv[3]) * tanhf(cn);
        cbuf[m * FDIM + j] = cn;
        bf16_t hb = __float2bfloat16(h);
        hA[(size_t)m * KK2 + j] = hb;
        hB[(size_t)m * KK2 + j] = hb;
        if (seqSlot) seqSlot[m * FDIM + j] = h;
    }
}

// copy latent -> out[:, :, 0:32, :]
__global__ void copy_lat(const float* __restrict__ latent, float* __restrict__ out) {
    size_t i = (size_t)blockIdx.x * blockDim.x + threadIdx.x; // float4 idx, 1048576 total
    if (i >= (size_t)1048576) return;
    size_t blk = i >> 8;       // (n*256+c)
    size_t within = i & 255;   // 256 float4 per (n,c) src block
    float4 v = ((const float4*)latent)[i];
    ((float4*)out)[blk * 512 + within] = v;
}

// gen half: out[n][c][32+t][h] = sum_cb seq_out[t][n][h*64+cb]*w_out[c][cb] + b_out[c]
__global__ __launch_bounds__(256) void gen_out(const float* __restrict__ seq_out,
                        const float* __restrict__ w_out, const float* __restrict__ b_out,
                        float* __restrict__ out) {
    __shared__ float row[32 * 65];  // [h][cb] padded (+1 col) to kill bank conflicts
    int b = blockIdx.x; int n = b >> 5, t = b & 31;
    const float* src = seq_out + ((size_t)t * NB + n) * FDIM;
    for (int i = threadIdx.x; i < FDIM; i += 256)
        row[(i >> 6) * 65 + (i & 63)] = src[i];
    __syncthreads();
    for (int it = 0; it < 32; ++it) {
        int o = it * 256 + threadIdx.x;  // 0..8191
        int c = o >> 5, h = o & 31;
        float acc = b_out[c];
#pragma unroll
        for (int cb = 0; cb < CBD; ++cb) acc += row[h * 65 + cb] * w_out[c * CBD + cb];
        out[(((size_t)n * CDIM + c) * 64 + 32 + t) * HGT + h] = acc;
    }
}

extern "C" void kernel_launch(void* const* d_in, const int* in_sizes, int n_in,
                              void* d_out, int out_size, void* d_ws, size_t ws_size,
                              hipStream_t stream) {
    const float* latent = (const float*)d_in[0];
    const float* w_in   = (const float*)d_in[1];
    const float* b_in   = (const float*)d_in[2];
    const float* w_ih0  = (const float*)d_in[3];
    const float* w_hh0  = (const float*)d_in[4];
    const float* b_ih0  = (const float*)d_in[5];
    const float* b_hh0  = (const float*)d_in[6];
    const float* w_ih1  = (const float*)d_in[7];
    const float* w_hh1  = (const float*)d_in[8];
    const float* b_ih1  = (const float*)d_in[9];
    const float* b_hh1  = (const float*)d_in[10];
    const float* w_out  = (const float*)d_in[11];
    const float* b_out  = (const float*)d_in[12];
    float* out = (float*)d_out;
    char* ws = (char*)d_ws;

    size_t off = 0;
    bf16_t* L0   = (bf16_t*)(ws + off); off += (size_t)GDIM * KK2 * 2;   // 64 MiB
    bf16_t* L1   = (bf16_t*)(ws + off); off += (size_t)GDIM * KK2 * 2;   // 64 MiB
    float*  X0   = (float*) (ws + off); off += (size_t)WSEQ * NB * GDIM * 4; // 16 MiB
    bf16_t* seqb = (bf16_t*)(ws + off); off += (size_t)WSEQ * NB * FDIM * 2; // 2 MiB
    float*  sqo  = (float*) (ws + off); off += (size_t)WSEQ * NB * FDIM * 4; // 4 MiB
    char*   zbase = ws + off;
    bf16_t* a0[2]; bf16_t* a1[2];
    a0[0] = (bf16_t*)(ws + off); off += (size_t)NB * KK2 * 2;
    a0[1] = (bf16_t*)(ws + off); off += (size_t)NB * KK2 * 2;
    a1[0] = (bf16_t*)(ws + off); off += (size_t)NB * KK2 * 2;
    a1[1] = (bf16_t*)(ws + off); off += (size_t)NB * KK2 * 2;
    float* c0 = (float*)(ws + off); off += (size_t)NB * FDIM * 4;
    float* c1 = (float*)(ws + off); off += (size_t)NB * FDIM * 4;
    size_t zbytes = (size_t)(ws + off - zbase);
    float* b0 = (float*)(ws + off); off += (size_t)GDIM * 4;
    float* b1 = (float*)(ws + off); off += (size_t)GDIM * 4;

    if (ws_size < off) {  // workspace too small: fail loudly with zeros
        hipMemsetAsync(d_out, 0, (size_t)out_size * 4, stream);
        return;
    }

    hipMemsetAsync(zbase, 0, zbytes, stream);
    pack_w<<<32768, 256, 0, stream>>>(w_ih0, w_hh0, w_ih1, w_hh1, L0, L1);
    bias_k<<<64, 256, 0, stream>>>(b_ih0, b_hh0, b_ih1, b_hh1, b0, b1);
    conv_in<<<512, 256, 0, stream>>>(latent, w_in, b_in, seqb);
    x0_gemm<<<512, 256, 0, stream>>>(seqb, L0, X0);

    for (int s = 0; s < 63; ++s) {
        int p = s & 1;
        bool fwd = (s < 32);
        // layer 0: g = [x|h0] @ L0cat^T (+X0pre for fwd) ; writes h0
        phase_k<<<128, 512, 0, stream>>>(
            a0[p], L0,
            fwd ? (X0 + (size_t)s * NB * GDIM) : nullptr,
            b0, c0,
            a0[1 - p] + FDIM,   // h0 -> next step's a0[:,2048:]
            a1[p],              // h0 -> this step's a1[:,0:2048]
            nullptr,
            fwd ? 64 : 0, fwd ? 64 : 128);
        // layer 1: g = [h0|h1] @ L1cat^T ; writes h1 (+ record)
        float* slot = nullptr;
        if (s == 31) slot = sqo;
        else if (s >= 32) slot = sqo + (size_t)(s - 31) * NB * FDIM;
        phase_k<<<128, 512, 0, stream>>>(
            a1[p], L1, nullptr, b1, c1,
            a1[1 - p] + FDIM,   // h1 -> next step's a1[:,2048:]
            a0[1 - p],          // h1 -> next step's x (AR input)
            slot,
            0, 128);
    }

    copy_lat<<<4096, 256, 0, stream>>>(latent, out);
    gen_out<<<512, 256, 0, stream>>>(sqo, w_out, b_out, out);
}

// Round 2
// 2021.157 us; speedup vs baseline: 1.4942x; 1.4942x over previous
//
#include <hip/hip_runtime.h>
#include <hip/hip_bf16.h>

#define NB   16      // batch
#define FDIM 2048    // lstm hidden
#define GDIM 8192    // 4*FDIM gates
#define KK2  4096    // concat K
#define WSEQ 32      // seq len
#define CDIM 256
#define CBD  64
#define HGT  32

typedef __bf16 bf16x8 __attribute__((ext_vector_type(8)));
typedef float  f32x4  __attribute__((ext_vector_type(4)));
typedef __hip_bfloat16 bf16_t;

__device__ __forceinline__ float sigf(float x) { return 1.f / (1.f + __expf(-x)); }

// ---------------------------------------------------------------------------
// Weight pack, gate-pair column interleave.
// Packed tile tIdx = jt*2 + p  (jt: 8-feature tile 0..255, p: gate pair 0..1)
// Tile column c (0..15): gate = 2p + (c>>3), feature j = jt*8 + (c&7)
// Original row r = gate*FDIM + j of the 8192x2048 [w_ih | w_hh] concat.
// Fragment: P[tIdx][kc][lane][8]; lane l supplies B[k=kc*32+(l>>4)*8+i][col=l&15]
// ---------------------------------------------------------------------------
__global__ void pack_w(const float* __restrict__ wih0, const float* __restrict__ whh0,
                       const float* __restrict__ wih1, const float* __restrict__ whh1,
                       bf16_t* __restrict__ L0, bf16_t* __restrict__ L1) {
    size_t idx = (size_t)blockIdx.x * blockDim.x + threadIdx.x; // 2*512*128*64 total
    int lane = idx & 63;
    int kc   = (idx >> 6) & 127;
    int tile = (idx >> 13) & 511;
    int mat  = (int)(idx >> 22);
    if (mat > 1) return;
    int c    = lane & 15;
    int p    = tile & 1;
    int jt   = tile >> 1;
    int gate = p * 2 + (c >> 3);
    int j    = jt * 8 + (c & 7);
    int r    = gate * FDIM + j;
    int kcol = kc * 32 + (lane >> 4) * 8;
    const float* wih = mat ? wih1 : wih0;
    const float* whh = mat ? whh1 : whh0;
    const float* src; int col;
    if (kcol < FDIM) { src = wih; col = kcol; } else { src = whh; col = kcol - FDIM; }
    const float* s = src + (size_t)r * FDIM + col;
    bf16_t* dst = (mat ? L1 : L0) + ((size_t)(tile * 128 + kc) * 64 + lane) * 8;
#pragma unroll
    for (int i = 0; i < 8; ++i) dst[i] = __float2bfloat16(s[i]);
}

__global__ void bias_k(const float* __restrict__ bih0, const float* __restrict__ bhh0,
                       const float* __restrict__ bih1, const float* __restrict__ bhh1,
                       float* __restrict__ b0, float* __restrict__ b1) {
    int i = blockIdx.x * blockDim.x + threadIdx.x;
    if (i < GDIM)            b0[i] = bih0[i] + bhh0[i];
    else if (i < 2 * GDIM) { int j = i - GDIM; b1[j] = bih1[j] + bhh1[j]; }
}

// ---------------------------------------------------------------------------
// 1x1 conv-in + pack sequence: seqb[t][n][f] (bf16), f = h*64 + cb
// ---------------------------------------------------------------------------
__global__ __launch_bounds__(256) void conv_in(const float* __restrict__ latent,
                        const float* __restrict__ w_in, const float* __restrict__ b_in,
                        bf16_t* __restrict__ seqb) {
    __shared__ float lat[CDIM * HGT]; // [c][h] 32 KiB
    int b = blockIdx.x; int n = b >> 5; int t = b & 31;
    int tid = threadIdx.x;
    for (int i = 0; i < 32; ++i) {
        int flat = i * 256 + tid;         // c*32+h
        int c = flat >> 5, h = flat & 31;
        lat[flat] = latent[(((size_t)n * CDIM + c) * WSEQ + t) * HGT + h];
    }
    __syncthreads();
    int cb = tid & 63;
    int hb = tid >> 6;
    float acc[8];
#pragma unroll
    for (int k = 0; k < 8; ++k) acc[k] = b_in[cb];
    for (int c = 0; c < CDIM; ++c) {
        float wv = w_in[cb * CDIM + c];
#pragma unroll
        for (int k = 0; k < 8; ++k) acc[k] += lat[c * HGT + (hb + k * 4)] * wv;
    }
#pragma unroll
    for (int k = 0; k < 8; ++k) {
        int f = k * 256 + tid;
        seqb[((size_t)t * NB + n) * FDIM + f] = __float2bfloat16(acc[k]);
    }
}

// ---------------------------------------------------------------------------
// X0pre[t][n][rr] = seq[t] @ w_ih0^T  in PACKED column order rr = tile*16+c.
// grid 1024: mtg = b>>7 (4 m-tiles each), ng = b&127; wave -> ntile = ng*4+w
// ---------------------------------------------------------------------------
__global__ __launch_bounds__(256) void x0_gemm(const bf16_t* __restrict__ seqb,
                                               const bf16_t* __restrict__ L0,
                                               float* __restrict__ x0) {
    int b = blockIdx.x;
    int mtg = b >> 7;                  // 0..7
    int ng  = b & 127;
    int wave = threadIdx.x >> 6;
    int l = threadIdx.x & 63;
    int ntile = ng * 4 + wave;
    int la = l & 15, kg = l >> 4;
    f32x4 acc[4];
#pragma unroll
    for (int i = 0; i < 4; ++i) acc[i] = (f32x4){0.f, 0.f, 0.f, 0.f};
    const bf16_t* Bbase = L0 + (size_t)ntile * 128 * 64 * 8;
#pragma unroll 4
    for (int kc = 0; kc < 64; ++kc) {   // K = 2048 (w_ih0 half)
        bf16x8 bf = *(const bf16x8*)(Bbase + ((size_t)kc * 64 + l) * 8);
#pragma unroll
        for (int i = 0; i < 4; ++i) {
            int mt = mtg * 4 + i;
            bf16x8 af = *(const bf16x8*)(seqb + ((size_t)(mt * 16 + la)) * FDIM + kc * 32 + kg * 8);
            acc[i] = __builtin_amdgcn_mfma_f32_16x16x32_bf16(af, bf, acc[i], 0, 0, 0);
        }
    }
#pragma unroll
    for (int i = 0; i < 4; ++i) {
        int mt = mtg * 4 + i;
#pragma unroll
        for (int q = 0; q < 4; ++q)
            x0[((size_t)(mt * 16 + kg * 4 + q)) * GDIM + ntile * 16 + la] = acc[i][q];
    }
}

// ---------------------------------------------------------------------------
// One LSTM phase. grid 256 blocks (jt = 8-feature tile), 1024 thr = 16 waves:
// wave = p(gate pair)*8 + ke(k-eighth). Templated total kc count (32-chunks).
// ---------------------------------------------------------------------------
template<int KCC>
__global__ __launch_bounds__(1024) void phase_k(
        const bf16_t* __restrict__ A, const bf16_t* __restrict__ Bp,
        const float* __restrict__ xpre, const float* __restrict__ bias,
        float* __restrict__ cbuf,
        bf16_t* __restrict__ hA, bf16_t* __restrict__ hB,
        float* __restrict__ seqSlot,
        int kcStart) {
    __shared__ float part[16][16][17];
    int jt = blockIdx.x;                 // 0..255
    int tid = threadIdx.x;
    int wave = tid >> 6, l = tid & 63;
    int p = wave >> 3, ke = wave & 7;
    int tIdx = jt * 2 + p;
    int la = l & 15, kg = l >> 4;
    constexpr int SL = KCC / 8;
    int kc0 = kcStart + ke * SL;
    f32x4 acc = (f32x4){0.f, 0.f, 0.f, 0.f};
    const bf16_t* Arow  = A + (size_t)la * KK2 + kc0 * 32 + kg * 8;
    const bf16_t* Bbase = Bp + ((size_t)(tIdx * 128 + kc0) * 64 + l) * 8;
#pragma unroll
    for (int kk = 0; kk < SL; ++kk) {
        bf16x8 af = *(const bf16x8*)(Arow + kk * 32);
        bf16x8 bf = *(const bf16x8*)(Bbase + (size_t)kk * 512);
        acc = __builtin_amdgcn_mfma_f32_16x16x32_bf16(af, bf, acc, 0, 0, 0);
    }
#pragma unroll
    for (int q = 0; q < 4; ++q) part[wave][kg * 4 + q][la] = acc[q];
    __syncthreads();
    if (tid < 128) {
        int m = tid >> 3, jj = tid & 7;
        float gi = 0.f, gf = 0.f, gg = 0.f, go = 0.f;
#pragma unroll
        for (int e = 0; e < 8; ++e) {
            gi += part[e][m][jj];
            gf += part[e][m][8 + jj];
            gg += part[8 + e][m][jj];
            go += part[8 + e][m][8 + jj];
        }
        int j = jt * 8 + jj;
        gi += bias[0 * FDIM + j];
        gf += bias[1 * FDIM + j];
        gg += bias[2 * FDIM + j];
        go += bias[3 * FDIM + j];
        if (xpre) {
            const float* xb = xpre + (size_t)m * GDIM + jt * 32;  // packed order
            gi += xb[jj]; gf += xb[8 + jj]; gg += xb[16 + jj]; go += xb[24 + jj];
        }
        float c  = cbuf[m * FDIM + j];
        float cn = sigf(gf) * c + sigf(gi) * tanhf(gg);
        float h  = sigf(go) * tanhf(cn);
        cbuf[m * FDIM + j] = cn;
        bf16_t hb = __float2bfloat16(h);
        hA[(size_t)m * KK2 + j] = hb;
        hB[(size_t)m * KK2 + j] = hb;
        if (seqSlot) seqSlot[m * FDIM + j] = h;
    }
}

// copy latent -> out[:, :, 0:32, :]
__global__ void copy_lat(const float* __restrict__ latent, float* __restrict__ out) {
    size_t i = (size_t)blockIdx.x * blockDim.x + threadIdx.x;
    if (i >= (size_t)1048576) return;
    size_t blk = i >> 8;
    size_t within = i & 255;
    float4 v = ((const float4*)latent)[i];
    ((float4*)out)[blk * 512 + within] = v;
}

// gen half: out[n][c][32+t][h] = sum_cb seq_out[t][n][h*64+cb]*w_out[c][cb] + b_out[c]
__global__ __launch_bounds__(256) void gen_out(const float* __restrict__ seq_out,
                        const float* __restrict__ w_out, const float* __restrict__ b_out,
                        float* __restrict__ out) {
    __shared__ float row[32 * 65];
    int b = blockIdx.x; int n = b >> 5, t = b & 31;
    const float* src = seq_out + ((size_t)t * NB + n) * FDIM;
    for (int i = threadIdx.x; i < FDIM; i += 256)
        row[(i >> 6) * 65 + (i & 63)] = src[i];
    __syncthreads();
    for (int it = 0; it < 32; ++it) {
        int o = it * 256 + threadIdx.x;
        int c = o >> 5, h = o & 31;
        float acc = b_out[c];
#pragma unroll
        for (int cb = 0; cb < CBD; ++cb) acc += row[h * 65 + cb] * w_out[c * CBD + cb];
        out[(((size_t)n * CDIM + c) * 64 + 32 + t) * HGT + h] = acc;
    }
}

extern "C" void kernel_launch(void* const* d_in, const int* in_sizes, int n_in,
                              void* d_out, int out_size, void* d_ws, size_t ws_size,
                              hipStream_t stream) {
    const float* latent = (const float*)d_in[0];
    const float* w_in   = (const float*)d_in[1];
    const float* b_in   = (const float*)d_in[2];
    const float* w_ih0  = (const float*)d_in[3];
    const float* w_hh0  = (const float*)d_in[4];
    const float* b_ih0  = (const float*)d_in[5];
    const float* b_hh0  = (const float*)d_in[6];
    const float* w_ih1  = (const float*)d_in[7];
    const float* w_hh1  = (const float*)d_in[8];
    const float* b_ih1  = (const float*)d_in[9];
    const float* b_hh1  = (const float*)d_in[10];
    const float* w_out  = (const float*)d_in[11];
    const float* b_out  = (const float*)d_in[12];
    float* out = (float*)d_out;
    char* ws = (char*)d_ws;

    size_t off = 0;
    bf16_t* L0   = (bf16_t*)(ws + off); off += (size_t)GDIM * KK2 * 2;   // 64 MiB
    bf16_t* L1   = (bf16_t*)(ws + off); off += (size_t)GDIM * KK2 * 2;   // 64 MiB
    float*  X0   = (float*) (ws + off); off += (size_t)WSEQ * NB * GDIM * 4; // 16 MiB
    bf16_t* seqb = (bf16_t*)(ws + off); off += (size_t)WSEQ * NB * FDIM * 2; // 2 MiB
    float*  sqo  = (float*) (ws + off); off += (size_t)WSEQ * NB * FDIM * 4; // 4 MiB
    char*   zbase = ws + off;
    bf16_t* a0[2]; bf16_t* a1[2];
    a0[0] = (bf16_t*)(ws + off); off += (size_t)NB * KK2 * 2;
    a0[1] = (bf16_t*)(ws + off); off += (size_t)NB * KK2 * 2;
    a1[0] = (bf16_t*)(ws + off); off += (size_t)NB * KK2 * 2;
    a1[1] = (bf16_t*)(ws + off); off += (size_t)NB * KK2 * 2;
    float* c0 = (float*)(ws + off); off += (size_t)NB * FDIM * 4;
    float* c1 = (float*)(ws + off); off += (size_t)NB * FDIM * 4;
    size_t zbytes = (size_t)(ws + off - zbase);
    float* b0 = (float*)(ws + off); off += (size_t)GDIM * 4;
    float* b1 = (float*)(ws + off); off += (size_t)GDIM * 4;

    if (ws_size < off) {
        hipMemsetAsync(d_out, 0, (size_t)out_size * 4, stream);
        return;
    }

    hipMemsetAsync(zbase, 0, zbytes, stream);
    pack_w<<<32768, 256, 0, stream>>>(w_ih0, w_hh0, w_ih1, w_hh1, L0, L1);
    bias_k<<<64, 256, 0, stream>>>(b_ih0, b_hh0, b_ih1, b_hh1, b0, b1);
    conv_in<<<512, 256, 0, stream>>>(latent, w_in, b_in, seqb);
    x0_gemm<<<1024, 256, 0, stream>>>(seqb, L0, X0);

    for (int s = 0; s < 63; ++s) {
        int p = s & 1;
        bool fwd = (s < 32);
        // layer 0: g = [x|h0] @ L0cat^T (+X0pre for fwd) ; writes h0
        if (fwd) {
            phase_k<64><<<256, 1024, 0, stream>>>(
                a0[p], L0, X0 + (size_t)s * NB * GDIM, b0, c0,
                a0[1 - p] + FDIM,   // h0 -> next step's a0[:,2048:]
                a1[p],              // h0 -> this step's a1[:,0:2048]
                nullptr, 64);
        } else {
            phase_k<128><<<256, 1024, 0, stream>>>(
                a0[p], L0, nullptr, b0, c0,
                a0[1 - p] + FDIM, a1[p], nullptr, 0);
        }
        // layer 1: g = [h0|h1] @ L1cat^T ; writes h1 (+ record)
        float* slot = nullptr;
        if (s == 31) slot = sqo;
        else if (s >= 32) slot = sqo + (size_t)(s - 31) * NB * FDIM;
        phase_k<128><<<256, 1024, 0, stream>>>(
            a1[p], L1, nullptr, b1, c1,
            a1[1 - p] + FDIM,   // h1 -> next step's a1[:,2048:]
            a0[1 - p],          // h1 -> next step's x (AR input)
            slot, 0);
    }

    copy_lat<<<4096, 256, 0, stream>>>(latent, out);
    gen_out<<<512, 256, 0, stream>>>(sqo, w_out, b_out, out);
}

// Round 3
// 1511.157 us; speedup vs baseline: 1.9985x; 1.3375x over previous
//
#include <hip/hip_runtime.h>
#include <hip/hip_bf16.h>

#define NB   16      // batch
#define FDIM 2048    // lstm hidden
#define GDIM 8192    // 4*FDIM gates
#define KK2  4096    // concat K
#define WSEQ 32      // seq len
#define CDIM 256
#define CBD  64
#define HGT  32

typedef float f32x4 __attribute__((ext_vector_type(4)));
typedef long  l64x2 __attribute__((ext_vector_type(2)));
typedef unsigned char u8;

__device__ __forceinline__ float sigf(float x) { return 1.f / (1.f + __expf(-x)); }

__device__ __forceinline__ u8 f32_to_fp8(float f) {
    int w = __builtin_amdgcn_cvt_pk_fp8_f32(f, f, 0, 0);
    return (u8)(w & 0xff);
}

// ---------------------------------------------------------------------------
// Weight pack -> fp8 e4m3, gate-pair column interleave, kc-PAIRED fragments.
// Tile tIdx = jt*2 + p. Column c(0..15): gate = 2p + (c>>3), j = jt*8 + (c&7).
// Layout: W[tile][kc2(0..63)][lane(0..63)][16B]; bytes 0-7 = kc=2*kc2 frag,
// bytes 8-15 = kc=2*kc2+1 frag; within a frag lane l holds
// B[k = kc*32 + (l>>4)*8 + i][col = l&15].  K concat: k<2048 -> w_ih else w_hh.
// ---------------------------------------------------------------------------
__global__ void pack_w(const float* __restrict__ wih0, const float* __restrict__ whh0,
                       const float* __restrict__ wih1, const float* __restrict__ whh1,
                       u8* __restrict__ W0, u8* __restrict__ W1) {
    unsigned int idx = blockIdx.x * 256 + threadIdx.x;  // 2*512*64*64 total
    int lane = idx & 63;
    int kc2  = (idx >> 6) & 63;
    int tile = (idx >> 12) & 511;
    int mat  = (idx >> 21) & 1;
    int c = lane & 15, kg = lane >> 4;
    int gate = (tile & 1) * 2 + (c >> 3);
    int r = gate * FDIM + (tile >> 1) * 8 + (c & 7);
    const float* wih = mat ? wih1 : wih0;
    const float* whh = mat ? whh1 : whh0;
    unsigned int words[4];
#pragma unroll
    for (int h = 0; h < 2; ++h) {
        int kb = kc2 * 64 + h * 32 + kg * 8;
        const float* s = (kb < FDIM) ? (wih + (size_t)r * FDIM + kb)
                                     : (whh + (size_t)r * FDIM + (kb - FDIM));
        int w0 = __builtin_amdgcn_cvt_pk_fp8_f32(s[0], s[1], 0, 0);
        w0     = __builtin_amdgcn_cvt_pk_fp8_f32(s[2], s[3], w0, 1);
        int w1 = __builtin_amdgcn_cvt_pk_fp8_f32(s[4], s[5], 0, 0);
        w1     = __builtin_amdgcn_cvt_pk_fp8_f32(s[6], s[7], w1, 1);
        words[h * 2] = (unsigned int)w0; words[h * 2 + 1] = (unsigned int)w1;
    }
    uint4* dst = (uint4*)((mat ? W1 : W0) + ((size_t)(tile * 64 + kc2) * 64 + lane) * 16);
    *dst = make_uint4(words[0], words[1], words[2], words[3]);
}

__global__ void bias_k(const float* __restrict__ bih0, const float* __restrict__ bhh0,
                       const float* __restrict__ bih1, const float* __restrict__ bhh1,
                       float* __restrict__ b0, float* __restrict__ b1) {
    int i = blockIdx.x * blockDim.x + threadIdx.x;
    if (i < GDIM)            b0[i] = bih0[i] + bhh0[i];
    else if (i < 2 * GDIM) { int j = i - GDIM; b1[j] = bih1[j] + bhh1[j]; }
}

// ---------------------------------------------------------------------------
// 1x1 conv-in + pack sequence: seqb[t][n][f] (fp8), f = h*64 + cb
// ---------------------------------------------------------------------------
__global__ __launch_bounds__(256) void conv_in(const float* __restrict__ latent,
                        const float* __restrict__ w_in, const float* __restrict__ b_in,
                        u8* __restrict__ seqb) {
    __shared__ float lat[CDIM * HGT]; // [c][h] 32 KiB
    int b = blockIdx.x; int n = b >> 5; int t = b & 31;
    int tid = threadIdx.x;
    for (int i = 0; i < 32; ++i) {
        int flat = i * 256 + tid;         // c*32+h
        int c = flat >> 5, h = flat & 31;
        lat[flat] = latent[(((size_t)n * CDIM + c) * WSEQ + t) * HGT + h];
    }
    __syncthreads();
    int cb = tid & 63;
    int hb = tid >> 6;
    float acc[8];
#pragma unroll
    for (int k = 0; k < 8; ++k) acc[k] = b_in[cb];
    for (int c = 0; c < CDIM; ++c) {
        float wv = w_in[cb * CDIM + c];
#pragma unroll
        for (int k = 0; k < 8; ++k) acc[k] += lat[c * HGT + (hb + k * 4)] * wv;
    }
#pragma unroll
    for (int k = 0; k < 8; ++k) {
        int f = k * 256 + tid;
        seqb[((size_t)t * NB + n) * FDIM + f] = f32_to_fp8(acc[k]);
    }
}

// ---------------------------------------------------------------------------
// X0pre[mrow][rr] = seq @ w_ih0^T in PACKED column order rr = ntile*16 + c.
// grid 512 = one block per ntile (B slice read ONCE); 4 waves x 8 m-tiles.
// K = 2048 -> kc2 0..31 of the packed tiles (w_ih half).
// ---------------------------------------------------------------------------
__global__ __launch_bounds__(256) void x0_gemm(const u8* __restrict__ seqb,
                                               const u8* __restrict__ W0,
                                               float* __restrict__ x0) {
    int ntile = blockIdx.x;            // 0..511
    int wave = threadIdx.x >> 6, l = threadIdx.x & 63;
    int la = l & 15, kg = l >> 4;
    f32x4 acc[8];
#pragma unroll
    for (int i = 0; i < 8; ++i) acc[i] = (f32x4){0.f, 0.f, 0.f, 0.f};
    const u8* Bb = W0 + (size_t)ntile * 64 * 64 * 16;
#pragma unroll 2
    for (int kc2 = 0; kc2 < 32; ++kc2) {
        l64x2 bp = *(const l64x2*)(Bb + ((size_t)kc2 * 64 + l) * 16);
#pragma unroll
        for (int i = 0; i < 8; ++i) {
            int row = (wave * 8 + i) * 16 + la;
            const u8* Ar = seqb + (size_t)row * FDIM + kc2 * 64 + kg * 8;
            long a0 = *(const long*)(Ar);
            long a1 = *(const long*)(Ar + 32);
            acc[i] = __builtin_amdgcn_mfma_f32_16x16x32_fp8_fp8(a0, bp.x, acc[i], 0, 0, 0);
            acc[i] = __builtin_amdgcn_mfma_f32_16x16x32_fp8_fp8(a1, bp.y, acc[i], 0, 0, 0);
        }
    }
#pragma unroll
    for (int i = 0; i < 8; ++i) {
        int mt = wave * 8 + i;
#pragma unroll
        for (int q = 0; q < 4; ++q)
            x0[((size_t)(mt * 16 + kg * 4 + q)) * GDIM + ntile * 16 + la] = acc[i][q];
    }
}

// ---------------------------------------------------------------------------
// One LSTM phase (fp8). grid 256 (jt), 1024 thr = 16 waves: wave = p*8 + ke.
// All loads hoisted ahead of the MFMA chain; 2 interleaved acc chains.
// A: fp8 [16][4096] row-major.  KCC = count of 32-wide kc chunks.
// ---------------------------------------------------------------------------
template<int KCC>
__global__ __launch_bounds__(1024) void phase_k(
        const u8* __restrict__ A, const u8* __restrict__ Bp,
        const float* __restrict__ xpre, const float* __restrict__ bias,
        float* __restrict__ cbuf,
        u8* __restrict__ hA, u8* __restrict__ hB,
        float* __restrict__ seqSlot,
        int kcStart) {
    __shared__ float part[16][16][17];
    int jt = blockIdx.x;                 // 0..255
    int tid = threadIdx.x;
    int wave = tid >> 6, l = tid & 63;
    int p = wave >> 3, ke = wave & 7;
    int tIdx = jt * 2 + p;
    int la = l & 15, kg = l >> 4;
    constexpr int SL  = KCC / 8;   // kc chunks per wave
    constexpr int SL2 = SL / 2;    // kc pairs per wave
    int kc0  = kcStart + ke * SL;
    int kc2b = kc0 >> 1;
    l64x2 bfr[SL2];
    long  afr[SL];
    const u8* Bb = Bp + ((size_t)(tIdx * 64 + kc2b) * 64 + l) * 16;
    const u8* Ab = A + (size_t)la * KK2 + kc0 * 32 + kg * 8;
#pragma unroll
    for (int i = 0; i < SL2; ++i) bfr[i] = *(const l64x2*)(Bb + (size_t)i * 1024);
#pragma unroll
    for (int i = 0; i < SL; ++i)  afr[i] = *(const long*)(Ab + i * 32);
    f32x4 acc0 = (f32x4){0.f, 0.f, 0.f, 0.f};
    f32x4 acc1 = (f32x4){0.f, 0.f, 0.f, 0.f};
#pragma unroll
    for (int i = 0; i < SL2; ++i) {
        acc0 = __builtin_amdgcn_mfma_f32_16x16x32_fp8_fp8(afr[2 * i],     bfr[i].x, acc0, 0, 0, 0);
        acc1 = __builtin_amdgcn_mfma_f32_16x16x32_fp8_fp8(afr[2 * i + 1], bfr[i].y, acc1, 0, 0, 0);
    }
    f32x4 acc = acc0 + acc1;
#pragma unroll
    for (int q = 0; q < 4; ++q) part[wave][kg * 4 + q][la] = acc[q];
    __syncthreads();
    if (tid < 128) {
        int m = tid >> 3, jj = tid & 7;
        float gi = 0.f, gf = 0.f, gg = 0.f, go = 0.f;
#pragma unroll
        for (int e = 0; e < 8; ++e) {
            gi += part[e][m][jj];
            gf += part[e][m][8 + jj];
            gg += part[8 + e][m][jj];
            go += part[8 + e][m][8 + jj];
        }
        int j = jt * 8 + jj;
        gi += bias[0 * FDIM + j];
        gf += bias[1 * FDIM + j];
        gg += bias[2 * FDIM + j];
        go += bias[3 * FDIM + j];
        if (xpre) {
            const float* xb = xpre + (size_t)m * GDIM + jt * 32;  // packed order
            gi += xb[jj]; gf += xb[8 + jj]; gg += xb[16 + jj]; go += xb[24 + jj];
        }
        float c  = cbuf[m * FDIM + j];
        float cn = sigf(gf) * c + sigf(gi) * tanhf(gg);
        float h  = sigf(go) * tanhf(cn);
        cbuf[m * FDIM + j] = cn;
        u8 hb = f32_to_fp8(h);
        hA[(size_t)m * KK2 + j] = hb;
        hB[(size_t)m * KK2 + j] = hb;
        if (seqSlot) seqSlot[m * FDIM + j] = h;
    }
}

// copy latent -> out[:, :, 0:32, :]
__global__ void copy_lat(const float* __restrict__ latent, float* __restrict__ out) {
    size_t i = (size_t)blockIdx.x * blockDim.x + threadIdx.x;
    if (i >= (size_t)1048576) return;
    size_t blk = i >> 8;
    size_t within = i & 255;
    float4 v = ((const float4*)latent)[i];
    ((float4*)out)[blk * 512 + within] = v;
}

// gen half: out[n][c][32+t][h] = sum_cb seq_out[t][n][h*64+cb]*w_out[c][cb] + b_out[c]
__global__ __launch_bounds__(256) void gen_out(const float* __restrict__ seq_out,
                        const float* __restrict__ w_out, const float* __restrict__ b_out,
                        float* __restrict__ out) {
    __shared__ float row[32 * 65];
    int b = blockIdx.x; int n = b >> 5, t = b & 31;
    const float* src = seq_out + ((size_t)t * NB + n) * FDIM;
    for (int i = threadIdx.x; i < FDIM; i += 256)
        row[(i >> 6) * 65 + (i & 63)] = src[i];
    __syncthreads();
    for (int it = 0; it < 32; ++it) {
        int o = it * 256 + threadIdx.x;
        int c = o >> 5, h = o & 31;
        float acc = b_out[c];
#pragma unroll
        for (int cb = 0; cb < CBD; ++cb) acc += row[h * 65 + cb] * w_out[c * CBD + cb];
        out[(((size_t)n * CDIM + c) * 64 + 32 + t) * HGT + h] = acc;
    }
}

extern "C" void kernel_launch(void* const* d_in, const int* in_sizes, int n_in,
                              void* d_out, int out_size, void* d_ws, size_t ws_size,
                              hipStream_t stream) {
    const float* latent = (const float*)d_in[0];
    const float* w_in   = (const float*)d_in[1];
    const float* b_in   = (const float*)d_in[2];
    const float* w_ih0  = (const float*)d_in[3];
    const float* w_hh0  = (const float*)d_in[4];
    const float* b_ih0  = (const float*)d_in[5];
    const float* b_hh0  = (const float*)d_in[6];
    const float* w_ih1  = (const float*)d_in[7];
    const float* w_hh1  = (const float*)d_in[8];
    const float* b_ih1  = (const float*)d_in[9];
    const float* b_hh1  = (const float*)d_in[10];
    const float* w_out  = (const float*)d_in[11];
    const float* b_out  = (const float*)d_in[12];
    float* out = (float*)d_out;
    char* ws = (char*)d_ws;

    size_t off = 0;
    u8*    W0   = (u8*)(ws + off); off += (size_t)512 * 64 * 64 * 16;       // 32 MiB
    u8*    W1   = (u8*)(ws + off); off += (size_t)512 * 64 * 64 * 16;       // 32 MiB
    float* X0   = (float*)(ws + off); off += (size_t)WSEQ * NB * GDIM * 4;  // 16 MiB
    u8*    seqb = (u8*)(ws + off); off += (size_t)WSEQ * NB * FDIM;         // 1 MiB
    float* sqo  = (float*)(ws + off); off += (size_t)WSEQ * NB * FDIM * 4;  // 4 MiB
    char*  zbase = ws + off;
    u8* a0[2]; u8* a1[2];
    a0[0] = (u8*)(ws + off); off += (size_t)NB * KK2;
    a0[1] = (u8*)(ws + off); off += (size_t)NB * KK2;
    a1[0] = (u8*)(ws + off); off += (size_t)NB * KK2;
    a1[1] = (u8*)(ws + off); off += (size_t)NB * KK2;
    float* c0 = (float*)(ws + off); off += (size_t)NB * FDIM * 4;
    float* c1 = (float*)(ws + off); off += (size_t)NB * FDIM * 4;
    size_t zbytes = (size_t)(ws + off - zbase);
    float* b0 = (float*)(ws + off); off += (size_t)GDIM * 4;
    float* b1 = (float*)(ws + off); off += (size_t)GDIM * 4;

    if (ws_size < off) {
        hipMemsetAsync(d_out, 0, (size_t)out_size * 4, stream);
        return;
    }

    hipMemsetAsync(zbase, 0, zbytes, stream);
    pack_w<<<16384, 256, 0, stream>>>(w_ih0, w_hh0, w_ih1, w_hh1, W0, W1);
    bias_k<<<64, 256, 0, stream>>>(b_ih0, b_hh0, b_ih1, b_hh1, b0, b1);
    conv_in<<<512, 256, 0, stream>>>(latent, w_in, b_in, seqb);
    x0_gemm<<<512, 256, 0, stream>>>(seqb, W0, X0);

    for (int s = 0; s < 63; ++s) {
        int p = s & 1;
        bool fwd = (s < 32);
        // layer 0: g = [x|h0] @ W0cat^T (+X0pre for fwd) ; writes h0
        if (fwd) {
            phase_k<64><<<256, 1024, 0, stream>>>(
                a0[p], W0, X0 + (size_t)s * NB * GDIM, b0, c0,
                a0[1 - p] + FDIM,   // h0 -> next step's a0[:,2048:]
                a1[p],              // h0 -> this step's a1[:,0:2048]
                nullptr, 64);
        } else {
            phase_k<128><<<256, 1024, 0, stream>>>(
                a0[p], W0, nullptr, b0, c0,
                a0[1 - p] + FDIM, a1[p], nullptr, 0);
        }
        // layer 1: g = [h0|h1] @ W1cat^T ; writes h1 (+ record)
        float* slot = nullptr;
        if (s == 31) slot = sqo;
        else if (s >= 32) slot = sqo + (size_t)(s - 31) * NB * FDIM;
        phase_k<128><<<256, 1024, 0, stream>>>(
            a1[p], W1, nullptr, b1, c1,
            a1[1 - p] + FDIM,   // h1 -> next step's a1[:,2048:]
            a0[1 - p],          // h1 -> next step's x (AR input)
            slot, 0);
    }

    copy_lat<<<4096, 256, 0, stream>>>(latent, out);
    gen_out<<<512, 256, 0, stream>>>(sqo, w_out, b_out, out);
}

// Round 4
// 995.734 us; speedup vs baseline: 3.0330x; 1.5176x over previous
//
#include <hip/hip_runtime.h>
#include <hip/hip_bf16.h>

#define NB   16      // batch
#define FDIM 2048    // lstm hidden
#define GDIM 8192    // 4*FDIM gates
#define KK2  4096    // concat K
#define WSEQ 32      // seq len
#define CDIM 256
#define CBD  64
#define HGT  32

typedef float f32x4 __attribute__((ext_vector_type(4)));
typedef long  l64x2 __attribute__((ext_vector_type(2)));
typedef unsigned char u8;

__device__ __forceinline__ float sigf(float x) { return 1.f / (1.f + __expf(-x)); }

__device__ __forceinline__ u8 f32_to_fp8(float f) {
    int w = __builtin_amdgcn_cvt_pk_fp8_f32(f, f, 0, 0);
    return (u8)(w & 0xff);
}

// ---------------------------------------------------------------------------
// Weight pack -> fp8 e4m3, gate-pair column interleave, kc-PAIRED fragments.
// Tile tIdx = jt*2 + p. Column c(0..15): gate = 2p + (c>>3), j = jt*8 + (c&7).
// W[tile][kc2(0..63)][lane][16B]: bytes0-7 = kc=2kc2, bytes8-15 = kc=2kc2+1.
// Within a frag lane l holds B[k=kc*32+(l>>4)*8+i][col=l&15]. k<2048: ih else hh.
// ---------------------------------------------------------------------------
__global__ void pack_w(const float* __restrict__ wih0, const float* __restrict__ whh0,
                       const float* __restrict__ wih1, const float* __restrict__ whh1,
                       u8* __restrict__ W0, u8* __restrict__ W1) {
    unsigned int idx = blockIdx.x * 256 + threadIdx.x;  // 2*512*64*64 total
    int lane = idx & 63;
    int kc2  = (idx >> 6) & 63;
    int tile = (idx >> 12) & 511;
    int mat  = (idx >> 21) & 1;
    int c = lane & 15, kg = lane >> 4;
    int gate = (tile & 1) * 2 + (c >> 3);
    int r = gate * FDIM + (tile >> 1) * 8 + (c & 7);
    const float* wih = mat ? wih1 : wih0;
    const float* whh = mat ? whh1 : whh0;
    unsigned int words[4];
#pragma unroll
    for (int h = 0; h < 2; ++h) {
        int kb = kc2 * 64 + h * 32 + kg * 8;
        const float* s = (kb < FDIM) ? (wih + (size_t)r * FDIM + kb)
                                     : (whh + (size_t)r * FDIM + (kb - FDIM));
        int w0 = __builtin_amdgcn_cvt_pk_fp8_f32(s[0], s[1], 0, 0);
        w0     = __builtin_amdgcn_cvt_pk_fp8_f32(s[2], s[3], w0, 1);
        int w1 = __builtin_amdgcn_cvt_pk_fp8_f32(s[4], s[5], 0, 0);
        w1     = __builtin_amdgcn_cvt_pk_fp8_f32(s[6], s[7], w1, 1);
        words[h * 2] = (unsigned int)w0; words[h * 2 + 1] = (unsigned int)w1;
    }
    uint4* dst = (uint4*)((mat ? W1 : W0) + ((size_t)(tile * 64 + kc2) * 64 + lane) * 16);
    *dst = make_uint4(words[0], words[1], words[2], words[3]);
}

__global__ void bias_k(const float* __restrict__ bih0, const float* __restrict__ bhh0,
                       const float* __restrict__ bih1, const float* __restrict__ bhh1,
                       float* __restrict__ b0, float* __restrict__ b1) {
    int i = blockIdx.x * blockDim.x + threadIdx.x;
    if (i < GDIM)            b0[i] = bih0[i] + bhh0[i];
    else if (i < 2 * GDIM) { int j = i - GDIM; b1[j] = bih1[j] + bhh1[j]; }
}

// ---------------------------------------------------------------------------
// 1x1 conv-in; emit seq in PACKED A-fragment layout:
//   seqbP[t] : [64 kc][64 lane][8B], lane = kg*16 + n, byte i -> k = kc*32+kg*8+i
// ---------------------------------------------------------------------------
__global__ __launch_bounds__(256) void conv_in(const float* __restrict__ latent,
                        const float* __restrict__ w_in, const float* __restrict__ b_in,
                        u8* __restrict__ seqbP) {
    __shared__ float lat[CDIM * HGT]; // [c][h] 32 KiB
    __shared__ float hv[FDIM];        // 8 KiB
    int b = blockIdx.x; int n = b >> 5; int t = b & 31;
    int tid = threadIdx.x;
    for (int i = 0; i < 32; ++i) {
        int flat = i * 256 + tid;         // c*32+h
        int c = flat >> 5, h = flat & 31;
        lat[flat] = latent[(((size_t)n * CDIM + c) * WSEQ + t) * HGT + h];
    }
    __syncthreads();
    int cb = tid & 63;
    int hb = tid >> 6;
    float acc[8];
#pragma unroll
    for (int k = 0; k < 8; ++k) acc[k] = b_in[cb];
    for (int c = 0; c < CDIM; ++c) {
        float wv = w_in[cb * CDIM + c];
#pragma unroll
        for (int k = 0; k < 8; ++k) acc[k] += lat[c * HGT + (hb + k * 4)] * wv;
    }
#pragma unroll
    for (int k = 0; k < 8; ++k) hv[k * 256 + tid] = acc[k];   // hv[f], f = h*64+cb
    __syncthreads();
    // thread tid packs f = tid*8 .. tid*8+7  (kc = tid>>2, kg = tid&3)
    union { u8 by[8]; long l; } pk;
#pragma unroll
    for (int i = 0; i < 8; ++i) pk.by[i] = f32_to_fp8(hv[tid * 8 + i]);
    *(long*)(seqbP + (size_t)t * 32768 + (tid >> 2) * 512 + (tid & 3) * 128 + n * 8) = pk.l;
}

// ---------------------------------------------------------------------------
// X0pre[t*16+m][rr] = seq[t] @ w_ih0^T, packed col order rr = ntile*16 + c.
// grid 512 = one block per ntile; 8 waves x 4 t-tiles; A packed & coalesced.
// ---------------------------------------------------------------------------
__global__ __launch_bounds__(512) void x0_gemm(const u8* __restrict__ seqbP,
                                               const u8* __restrict__ W0,
                                               float* __restrict__ x0) {
    int ntile = blockIdx.x;            // 0..511
    int wave = threadIdx.x >> 6, l = threadIdx.x & 63;
    int la = l & 15, kg = l >> 4;
    f32x4 acc[4];
#pragma unroll
    for (int i = 0; i < 4; ++i) acc[i] = (f32x4){0.f, 0.f, 0.f, 0.f};
    const u8* Bb = W0 + (size_t)ntile * 64 * 64 * 16;
#pragma unroll 2
    for (int kc2 = 0; kc2 < 32; ++kc2) {
        l64x2 bp = *(const l64x2*)(Bb + ((size_t)kc2 * 64 + l) * 16);
#pragma unroll
        for (int i = 0; i < 4; ++i) {
            int t = wave * 4 + i;
            const u8* Ab = seqbP + (size_t)t * 32768 + (size_t)(2 * kc2) * 512 + l * 8;
            long a0 = *(const long*)Ab;
            long a1 = *(const long*)(Ab + 512);
            acc[i] = __builtin_amdgcn_mfma_f32_16x16x32_fp8_fp8(a0, bp.x, acc[i], 0, 0, 0);
            acc[i] = __builtin_amdgcn_mfma_f32_16x16x32_fp8_fp8(a1, bp.y, acc[i], 0, 0, 0);
        }
    }
#pragma unroll
    for (int i = 0; i < 4; ++i) {
        int t = wave * 4 + i;
#pragma unroll
        for (int q = 0; q < 4; ++q)
            x0[((size_t)(t * 16 + kg * 4 + q)) * GDIM + ntile * 16 + la] = acc[i][q];
    }
}

// ---------------------------------------------------------------------------
// LSTM phase body. A is a PACKED activation buffer [128 kc][64 lane][8B].
// 16 waves: wave = p(gate pair)*8 + ke. Cell tail writes h into the h-half
// (byte 32768+) of hA and the x-half (byte 0+) of hB, each 128B contiguous.
// ---------------------------------------------------------------------------
template<int KCC>
__device__ __forceinline__ void phase_body(
        int jt, int tid,
        const u8* __restrict__ A, const u8* __restrict__ Bp,
        const float* __restrict__ xpre, const float* __restrict__ bias,
        float* __restrict__ cbuf, u8* __restrict__ hA, u8* __restrict__ hB,
        float* __restrict__ seqSlot, int kcStart, float* part) {
    int wave = tid >> 6, l = tid & 63;
    int p = wave >> 3, ke = wave & 7;
    int tIdx = jt * 2 + p;
    int la = l & 15, kg = l >> 4;
    constexpr int SL  = KCC / 8;   // kc chunks per wave
    constexpr int SL2 = SL / 2;
    int kc0 = kcStart + ke * SL;
    l64x2 bfr[SL2];
    long  afr[SL];
    const u8* Bb = Bp + ((size_t)(tIdx * 64 + (kc0 >> 1)) * 64 + l) * 16;
    const u8* Ab = A + (size_t)kc0 * 512 + l * 8;
#pragma unroll
    for (int i = 0; i < SL2; ++i) bfr[i] = *(const l64x2*)(Bb + (size_t)i * 1024);
#pragma unroll
    for (int i = 0; i < SL; ++i)  afr[i] = *(const long*)(Ab + (size_t)i * 512);
    f32x4 acc0 = (f32x4){0.f, 0.f, 0.f, 0.f};
    f32x4 acc1 = (f32x4){0.f, 0.f, 0.f, 0.f};
#pragma unroll
    for (int i = 0; i < SL2; ++i) {
        acc0 = __builtin_amdgcn_mfma_f32_16x16x32_fp8_fp8(afr[2 * i],     bfr[i].x, acc0, 0, 0, 0);
        acc1 = __builtin_amdgcn_mfma_f32_16x16x32_fp8_fp8(afr[2 * i + 1], bfr[i].y, acc1, 0, 0, 0);
    }
    f32x4 acc = acc0 + acc1;
#pragma unroll
    for (int q = 0; q < 4; ++q) part[((size_t)wave * 16 + kg * 4 + q) * 17 + la] = acc[q];
    __syncthreads();
    if (tid < 128) {
        int m = tid >> 3, jj = tid & 7;
        float gi = 0.f, gf = 0.f, gg = 0.f, go = 0.f;
#pragma unroll
        for (int e = 0; e < 8; ++e) {
            gi += part[((size_t)e * 16 + m) * 17 + jj];
            gf += part[((size_t)e * 16 + m) * 17 + 8 + jj];
            gg += part[((size_t)(8 + e) * 16 + m) * 17 + jj];
            go += part[((size_t)(8 + e) * 16 + m) * 17 + 8 + jj];
        }
        int j = jt * 8 + jj;
        gi += bias[0 * FDIM + j];
        gf += bias[1 * FDIM + j];
        gg += bias[2 * FDIM + j];
        go += bias[3 * FDIM + j];
        if (xpre) {
            const float* xb = xpre + (size_t)m * GDIM + jt * 32;  // packed order
            gi += xb[jj]; gf += xb[8 + jj]; gg += xb[16 + jj]; go += xb[24 + jj];
        }
        float c  = cbuf[m * FDIM + j];
        float cn = sigf(gf) * c + sigf(gi) * tanhf(gg);
        float h  = sigf(go) * tanhf(cn);
        cbuf[m * FDIM + j] = cn;
        u8 hb = f32_to_fp8(h);
        int pos = (jt >> 2) * 512 + (jt & 3) * 128 + tid;
        hA[32768 + pos] = hb;   // h-half (cols 2048+j)
        hB[pos] = hb;           // x-half (cols j)
        if (seqSlot) seqSlot[m * FDIM + j] = h;
    }
}

template<int KCC>
__global__ __launch_bounds__(1024) void phase_k(
        const u8* __restrict__ A, const u8* __restrict__ Bp,
        const float* __restrict__ xpre, const float* __restrict__ bias,
        float* __restrict__ cbuf, u8* __restrict__ hA, u8* __restrict__ hB,
        float* __restrict__ seqSlot, int kcStart) {
    __shared__ float part[16 * 16 * 17];
    phase_body<KCC>(blockIdx.x, threadIdx.x, A, Bp, xpre, bias, cbuf, hA, hB,
                    seqSlot, kcStart, part);
}

// Fused forward pair: blocks 0-255 do layer1[s]; blocks 256-511 do layer0[s+1]
// (fwd layer0 reads only the h-half, so no dependency on layer1's writes).
__global__ __launch_bounds__(1024) void fused_fwd(
        const u8* __restrict__ A1, const u8* __restrict__ W1p,
        const float* __restrict__ bias1, float* __restrict__ c1v,
        u8* __restrict__ hA1, u8* __restrict__ hB1,
        const u8* __restrict__ A0, const u8* __restrict__ W0p,
        const float* __restrict__ xpre0, const float* __restrict__ bias0,
        float* __restrict__ c0v, u8* __restrict__ hA0, u8* __restrict__ hB0) {
    __shared__ float part[16 * 16 * 17];
    int jt = blockIdx.x & 255;
    if (blockIdx.x < 256)
        phase_body<128>(jt, threadIdx.x, A1, W1p, nullptr, bias1, c1v, hA1, hB1,
                        nullptr, 0, part);
    else
        phase_body<64>(jt, threadIdx.x, A0, W0p, xpre0, bias0, c0v, hA0, hB0,
                       nullptr, 64, part);
}

// copy latent -> out[:, :, 0:32, :]
__global__ void copy_lat(const float* __restrict__ latent, float* __restrict__ out) {
    size_t i = (size_t)blockIdx.x * blockDim.x + threadIdx.x;
    if (i >= (size_t)1048576) return;
    size_t blk = i >> 8;
    size_t within = i & 255;
    float4 v = ((const float4*)latent)[i];
    ((float4*)out)[blk * 512 + within] = v;
}

// gen half: out[n][c][32+t][h] = sum_cb seq_out[t][n][h*64+cb]*w_out[c][cb] + b_out[c]
__global__ __launch_bounds__(256) void gen_out(const float* __restrict__ seq_out,
                        const float* __restrict__ w_out, const float* __restrict__ b_out,
                        float* __restrict__ out) {
    __shared__ float row[32 * 65];
    int b = blockIdx.x; int n = b >> 5, t = b & 31;
    const float* src = seq_out + ((size_t)t * NB + n) * FDIM;
    for (int i = threadIdx.x; i < FDIM; i += 256)
        row[(i >> 6) * 65 + (i & 63)] = src[i];
    __syncthreads();
    for (int it = 0; it < 32; ++it) {
        int o = it * 256 + threadIdx.x;
        int c = o >> 5, h = o & 31;
        float acc = b_out[c];
#pragma unroll
        for (int cb = 0; cb < CBD; ++cb) acc += row[h * 65 + cb] * w_out[c * CBD + cb];
        out[(((size_t)n * CDIM + c) * 64 + 32 + t) * HGT + h] = acc;
    }
}

extern "C" void kernel_launch(void* const* d_in, const int* in_sizes, int n_in,
                              void* d_out, int out_size, void* d_ws, size_t ws_size,
                              hipStream_t stream) {
    const float* latent = (const float*)d_in[0];
    const float* w_in   = (const float*)d_in[1];
    const float* b_in   = (const float*)d_in[2];
    const float* w_ih0  = (const float*)d_in[3];
    const float* w_hh0  = (const float*)d_in[4];
    const float* b_ih0  = (const float*)d_in[5];
    const float* b_hh0  = (const float*)d_in[6];
    const float* w_ih1  = (const float*)d_in[7];
    const float* w_hh1  = (const float*)d_in[8];
    const float* b_ih1  = (const float*)d_in[9];
    const float* b_hh1  = (const float*)d_in[10];
    const float* w_out  = (const float*)d_in[11];
    const float* b_out  = (const float*)d_in[12];
    float* out = (float*)d_out;
    char* ws = (char*)d_ws;

    size_t off = 0;
    u8*    W0   = (u8*)(ws + off); off += (size_t)512 * 64 * 64 * 16;       // 32 MiB
    u8*    W1   = (u8*)(ws + off); off += (size_t)512 * 64 * 64 * 16;       // 32 MiB
    float* X0   = (float*)(ws + off); off += (size_t)WSEQ * NB * GDIM * 4;  // 16 MiB
    u8*    seqbP= (u8*)(ws + off); off += (size_t)WSEQ * 32768;             // 1 MiB
    float* sqo  = (float*)(ws + off); off += (size_t)WSEQ * NB * FDIM * 4;  // 4 MiB
    char*  zbase = ws + off;
    u8* a0[2]; u8* a1[2];
    a0[0] = (u8*)(ws + off); off += 65536;   // packed [128kc][64][8]
    a0[1] = (u8*)(ws + off); off += 65536;
    a1[0] = (u8*)(ws + off); off += 65536;
    a1[1] = (u8*)(ws + off); off += 65536;
    float* c0 = (float*)(ws + off); off += (size_t)NB * FDIM * 4;
    float* c1 = (float*)(ws + off); off += (size_t)NB * FDIM * 4;
    size_t zbytes = (size_t)(ws + off - zbase);
    float* b0 = (float*)(ws + off); off += (size_t)GDIM * 4;
    float* b1 = (float*)(ws + off); off += (size_t)GDIM * 4;

    if (ws_size < off) {
        hipMemsetAsync(d_out, 0, (size_t)out_size * 4, stream);
        return;
    }

    hipMemsetAsync(zbase, 0, zbytes, stream);
    pack_w<<<16384, 256, 0, stream>>>(w_ih0, w_hh0, w_ih1, w_hh1, W0, W1);
    bias_k<<<64, 256, 0, stream>>>(b_ih0, b_hh0, b_ih1, b_hh1, b0, b1);
    conv_in<<<512, 256, 0, stream>>>(latent, w_in, b_in, seqbP);
    x0_gemm<<<512, 512, 0, stream>>>(seqbP, W0, X0);

    // s=0, layer0 (p=0): reads a0[0] h-half (zeros); h0[0] -> a0[1].h, a1[0].x
    phase_k<64><<<256, 1024, 0, stream>>>(a0[0], W0, X0, b0, c0,
                                          a0[1], a1[0], nullptr, 64);
    // fwd pairs s=0..30: L1[s] + L0[s+1]
    for (int s = 0; s <= 30; ++s) {
        int p = s & 1;
        fused_fwd<<<512, 1024, 0, stream>>>(
            a1[p], W1, b1, c1, a1[1 - p], a0[1 - p],                 // L1[s]
            a0[1 - p], W0, X0 + (size_t)(s + 1) * NB * GDIM, b0, c0, // L0[s+1]
            a0[p], a1[1 - p]);
    }
    // s=31, layer1 (p=1): records first output
    phase_k<128><<<256, 1024, 0, stream>>>(a1[1], W1, nullptr, b1, c1,
                                           a1[0], a0[0], sqo, 0);
    // AR region s=32..62
    for (int s = 32; s < 63; ++s) {
        int p = s & 1;
        phase_k<128><<<256, 1024, 0, stream>>>(a0[p], W0, nullptr, b0, c0,
                                               a0[1 - p], a1[p], nullptr, 0);
        phase_k<128><<<256, 1024, 0, stream>>>(a1[p], W1, nullptr, b1, c1,
                                               a1[1 - p], a0[1 - p],
                                               sqo + (size_t)(s - 31) * NB * FDIM, 0);
    }

    copy_lat<<<4096, 256, 0, stream>>>(latent, out);
    gen_out<<<512, 256, 0, stream>>>(sqo, w_out, b_out, out);
}